// Round 1
// baseline (167.856 us; speedup 1.0000x reference)
//
#include <hip/hip_runtime.h>
#include <cmath>

#define WS   11
#define PAD  5
#define NX   160
#define NB   2
#define TH   32
#define TW   32
#define NF   5
#define DCHUNK 40

static const long long PLANE = (long long)NB * NX * NX * NX; // 8,192,000 per field

struct GaussW { float g[WS]; };

__constant__ const float C1v = 1.0e-4f;   // (0.01*1.0)^2
__constant__ const float C2v = 9.0e-4f;   // (0.03*1.0)^2

// Kernel 1: per (b,d) slice, compute 5 fields (x,y,x2,y2,xy), blur along W then H,
// write planar field volumes A[f][b][d][h][w].
__global__ __launch_bounds__(256) void k_wh(const float* __restrict__ x,
                                            const float* __restrict__ y,
                                            float* __restrict__ A,
                                            GaussW gw) {
    __shared__ float sf[NF][TH + 2*PAD][TW + 2*PAD];   // 5*42*42*4 = 35.3 KB
    __shared__ float mid[NF][TH + 2*PAD][TW];          // 5*42*32*4 = 26.9 KB

    const int tid = threadIdx.x;
    const int b  = blockIdx.z / NX;
    const int d  = blockIdx.z % NX;
    const int h0 = blockIdx.y * TH;
    const int w0 = blockIdx.x * TW;
    const long long slice = (long long)(b * NX + d) * (NX * NX);

    // stage x,y tile + halo; build 5 raw fields in LDS
    for (int idx = tid; idx < (TH + 10) * (TW + 10); idx += 256) {
        const int r = idx / (TW + 10), c = idx % (TW + 10);
        const int gh = h0 - PAD + r;
        const int gww = w0 - PAD + c;
        float xv = 0.f, yv = 0.f;
        if (gh >= 0 && gh < NX && gww >= 0 && gww < NX) {
            const long long o = slice + (long long)gh * NX + gww;
            xv = x[o]; yv = y[o];
        }
        sf[0][r][c] = xv;
        sf[1][r][c] = yv;
        sf[2][r][c] = xv * xv;
        sf[3][r][c] = yv * yv;
        sf[4][r][c] = xv * yv;
    }
    __syncthreads();

    // blur along W for all (TH+10) rows
    for (int idx = tid; idx < (TH + 10) * TW; idx += 256) {
        const int r = idx / TW, c = idx % TW;
        float a0 = 0.f, a1 = 0.f, a2 = 0.f, a3 = 0.f, a4 = 0.f;
        #pragma unroll
        for (int k = 0; k < WS; ++k) {
            const float gk = gw.g[k];
            a0 += gk * sf[0][r][c + k];
            a1 += gk * sf[1][r][c + k];
            a2 += gk * sf[2][r][c + k];
            a3 += gk * sf[3][r][c + k];
            a4 += gk * sf[4][r][c + k];
        }
        mid[0][r][c] = a0; mid[1][r][c] = a1; mid[2][r][c] = a2;
        mid[3][r][c] = a3; mid[4][r][c] = a4;
    }
    __syncthreads();

    // blur along H, store to global planar volumes
    for (int idx = tid; idx < TH * TW; idx += 256) {
        const int r = idx / TW, c = idx % TW;
        float a0 = 0.f, a1 = 0.f, a2 = 0.f, a3 = 0.f, a4 = 0.f;
        #pragma unroll
        for (int k = 0; k < WS; ++k) {
            const float gk = gw.g[k];
            a0 += gk * mid[0][r + k][c];
            a1 += gk * mid[1][r + k][c];
            a2 += gk * mid[2][r + k][c];
            a3 += gk * mid[3][r + k][c];
            a4 += gk * mid[4][r + k][c];
        }
        const long long o = slice + (long long)(h0 + r) * NX + (w0 + c);
        A[o]             = a0;
        A[PLANE + o]     = a1;
        A[2 * PLANE + o] = a2;
        A[3 * PLANE + o] = a3;
        A[4 * PLANE + o] = a4;
    }
}

// Kernel 2: blur along D with a register sliding window (static indexing only),
// compute SSIM per element, accumulate, block-reduce into partials.
__global__ __launch_bounds__(256) void k_d(const float* __restrict__ A,
                                           float* __restrict__ partial,
                                           GaussW gw) {
    const int tid = threadIdx.x;
    const long long gidx = (long long)blockIdx.x * 256 + tid;
    const int NCOL = NB * NX * NX;                 // 51200 columns
    const int chunk = (int)(gidx / NCOL);          // which D chunk
    const int col   = (int)(gidx % NCOL);
    const int b  = col / (NX * NX);
    const int hw = col % (NX * NX);
    const long long base = (long long)b * (NX * NX * NX) + hw;  // + d*NX*NX
    const int d0 = chunk * DCHUNK;

    float win[NF][WS];
    #pragma unroll
    for (int i = 0; i < WS; ++i) {
        const int di = d0 - PAD + i;
        const bool ok = (di >= 0 && di < NX);
        const long long o = base + (long long)(ok ? di : 0) * (NX * NX);
        #pragma unroll
        for (int f = 0; f < NF; ++f)
            win[f][i] = ok ? A[(long long)f * PLANE + o] : 0.f;
    }

    float acc = 0.f;
    for (int dd = 0; dd < DCHUNK; ++dd) {
        float m[NF];
        #pragma unroll
        for (int f = 0; f < NF; ++f) {
            float s = 0.f;
            #pragma unroll
            for (int i = 0; i < WS; ++i) s += gw.g[i] * win[f][i];
            m[f] = s;
        }
        const float mux = m[0], muy = m[1];
        const float mux2 = mux * mux, muy2 = muy * muy, muxy = mux * muy;
        const float sx  = m[2] - mux2;
        const float sy  = m[3] - muy2;
        const float sxy = m[4] - muxy;
        const float num = (2.f * muxy + C1v) * (2.f * sxy + C2v);
        const float den = (mux2 + muy2 + C1v) * (sx + sy + C2v);
        acc += num / den;

        // shift window, load next plane (d0+dd+6)
        const int dn = d0 + dd + PAD + 1;
        const bool ok = (dn < NX);
        const long long o = base + (long long)(ok ? dn : 0) * (NX * NX);
        #pragma unroll
        for (int f = 0; f < NF; ++f) {
            #pragma unroll
            for (int i = 0; i < WS - 1; ++i) win[f][i] = win[f][i + 1];
            win[f][WS - 1] = ok ? A[(long long)f * PLANE + o] : 0.f;
        }
    }

    // wave reduce (64 lanes) then cross-wave via LDS
    for (int off = 32; off > 0; off >>= 1) acc += __shfl_down(acc, off, 64);
    __shared__ float wsum[4];
    if ((tid & 63) == 0) wsum[tid >> 6] = acc;
    __syncthreads();
    if (tid == 0) partial[blockIdx.x] = wsum[0] + wsum[1] + wsum[2] + wsum[3];
}

// Kernel 3: reduce partials (double), write mean.
__global__ __launch_bounds__(256) void k_red(const float* __restrict__ partial,
                                             int n, float* __restrict__ out) {
    double s = 0.0;
    for (int i = threadIdx.x; i < n; i += 256) s += (double)partial[i];
    __shared__ double sd[256];
    sd[threadIdx.x] = s;
    __syncthreads();
    for (int st = 128; st > 0; st >>= 1) {
        if (threadIdx.x < st) sd[threadIdx.x] += sd[threadIdx.x + st];
        __syncthreads();
    }
    if (threadIdx.x == 0)
        out[0] = (float)(sd[0] / (double)((long long)NB * NX * NX * NX));
}

extern "C" void kernel_launch(void* const* d_in, const int* in_sizes, int n_in,
                              void* d_out, int out_size, void* d_ws, size_t ws_size,
                              hipStream_t stream) {
    const float* x = (const float*)d_in[0];
    const float* y = (const float*)d_in[1];
    float* A = (float*)d_ws;
    float* partial = (float*)((char*)d_ws + (size_t)NF * PLANE * sizeof(float));

    GaussW gw;
    {
        float tmp[WS]; float s = 0.f;
        for (int i = 0; i < WS; ++i) {
            const double e = exp(-(double)((i - PAD) * (i - PAD)) / 4.5);
            tmp[i] = (float)e; s += tmp[i];
        }
        for (int i = 0; i < WS; ++i) gw.g[i] = tmp[i] / s;
    }

    dim3 g1(NX / TW, NX / TH, NB * NX);   // (5,5,320)
    k_wh<<<g1, 256, 0, stream>>>(x, y, A, gw);

    const int nblk2 = (NB * NX * NX * (NX / DCHUNK)) / 256;  // 800
    k_d<<<nblk2, 256, 0, stream>>>(A, partial, gw);

    k_red<<<1, 256, 0, stream>>>(partial, nblk2, (float*)d_out);
}

// Round 2
// 117.035 us; speedup vs baseline: 1.4342x; 1.4342x over previous
//
#include <hip/hip_runtime.h>
#include <cmath>

#define WS   11
#define PAD  5
#define NX   160
#define NB   2
#define TH   20
#define TW   32
#define SH   (TH + 2*PAD)   // 30
#define SW   (TW + 2*PAD)   // 42
#define NF   5
#define DCHUNK 40

static const long long PLANE = (long long)NB * NX * NX * NX; // 8,192,000 per field

struct GaussW { float g[WS]; };

__constant__ const float C1v = 1.0e-4f;   // (0.01*1.0)^2
__constant__ const float C2v = 9.0e-4f;   // (0.03*1.0)^2

// Kernel 1: per (b,d) slice, stage x,y tile (+halo) in LDS, form 5 fields on the
// fly in the W-blur, H-blur, write planar field volumes A[f][b][d][h][w].
// LDS = 2*30*42*4 + 5*30*32*4 = 29.3 KB -> 4 blocks/CU (VGPR-band capped), 50% occ.
__global__ __launch_bounds__(256) void k_wh(const float* __restrict__ x,
                                            const float* __restrict__ y,
                                            float* __restrict__ A,
                                            GaussW gw) {
    __shared__ float sx[SH][SW];          // 5.04 KB
    __shared__ float sy[SH][SW];          // 5.04 KB
    __shared__ float mid[NF][SH][TW];     // 19.2 KB

    const int tid = threadIdx.x;
    const int b  = blockIdx.z / NX;
    const int d  = blockIdx.z % NX;
    const int h0 = blockIdx.y * TH;
    const int w0 = blockIdx.x * TW;
    const long long slice = (long long)(b * NX + d) * (NX * NX);

    // stage x,y tile + halo (zero-padded at volume edges)
    for (int idx = tid; idx < SH * SW; idx += 256) {
        const int r = idx / SW, c = idx % SW;
        const int gh = h0 - PAD + r;
        const int gww = w0 - PAD + c;
        float xv = 0.f, yv = 0.f;
        if (gh >= 0 && gh < NX && gww >= 0 && gww < NX) {
            const long long o = slice + (long long)gh * NX + gww;
            xv = x[o]; yv = y[o];
        }
        sx[r][c] = xv;
        sy[r][c] = yv;
    }
    __syncthreads();

    // blur along W for all SH rows; build 5 fields on the fly
    for (int idx = tid; idx < SH * TW; idx += 256) {
        const int r = idx >> 5, c = idx & 31;
        float a0 = 0.f, a1 = 0.f, a2 = 0.f, a3 = 0.f, a4 = 0.f;
        #pragma unroll
        for (int k = 0; k < WS; ++k) {
            const float gk = gw.g[k];
            const float xv = sx[r][c + k];
            const float yv = sy[r][c + k];
            a0 += gk * xv;
            a1 += gk * yv;
            a2 += gk * xv * xv;
            a3 += gk * yv * yv;
            a4 += gk * xv * yv;
        }
        mid[0][r][c] = a0; mid[1][r][c] = a1; mid[2][r][c] = a2;
        mid[3][r][c] = a3; mid[4][r][c] = a4;
    }
    __syncthreads();

    // blur along H, store to global planar volumes
    for (int idx = tid; idx < TH * TW; idx += 256) {
        const int r = idx >> 5, c = idx & 31;
        float a0 = 0.f, a1 = 0.f, a2 = 0.f, a3 = 0.f, a4 = 0.f;
        #pragma unroll
        for (int k = 0; k < WS; ++k) {
            const float gk = gw.g[k];
            a0 += gk * mid[0][r + k][c];
            a1 += gk * mid[1][r + k][c];
            a2 += gk * mid[2][r + k][c];
            a3 += gk * mid[3][r + k][c];
            a4 += gk * mid[4][r + k][c];
        }
        const long long o = slice + (long long)(h0 + r) * NX + (w0 + c);
        A[o]             = a0;
        A[PLANE + o]     = a1;
        A[2 * PLANE + o] = a2;
        A[3 * PLANE + o] = a3;
        A[4 * PLANE + o] = a4;
    }
}

// Kernel 2: blur along D with a register sliding window (static indexing only),
// compute SSIM per element, accumulate, block-reduce into partials.
__global__ __launch_bounds__(256) void k_d(const float* __restrict__ A,
                                           float* __restrict__ partial,
                                           GaussW gw) {
    const int tid = threadIdx.x;
    const long long gidx = (long long)blockIdx.x * 256 + tid;
    const int NCOL = NB * NX * NX;                 // 51200 columns
    const int chunk = (int)(gidx / NCOL);          // which D chunk
    const int col   = (int)(gidx % NCOL);
    const int b  = col / (NX * NX);
    const int hw = col % (NX * NX);
    const long long base = (long long)b * (NX * NX * NX) + hw;  // + d*NX*NX
    const int d0 = chunk * DCHUNK;

    float win[NF][WS];
    #pragma unroll
    for (int i = 0; i < WS; ++i) {
        const int di = d0 - PAD + i;
        const bool ok = (di >= 0 && di < NX);
        const long long o = base + (long long)(ok ? di : 0) * (NX * NX);
        #pragma unroll
        for (int f = 0; f < NF; ++f)
            win[f][i] = ok ? A[(long long)f * PLANE + o] : 0.f;
    }

    float acc = 0.f;
    for (int dd = 0; dd < DCHUNK; ++dd) {
        float m[NF];
        #pragma unroll
        for (int f = 0; f < NF; ++f) {
            float s = 0.f;
            #pragma unroll
            for (int i = 0; i < WS; ++i) s += gw.g[i] * win[f][i];
            m[f] = s;
        }
        const float mux = m[0], muy = m[1];
        const float mux2 = mux * mux, muy2 = muy * muy, muxy = mux * muy;
        const float sx_  = m[2] - mux2;
        const float sy_  = m[3] - muy2;
        const float sxy = m[4] - muxy;
        const float num = (2.f * muxy + C1v) * (2.f * sxy + C2v);
        const float den = (mux2 + muy2 + C1v) * (sx_ + sy_ + C2v);
        acc += num / den;

        // shift window, load next plane (d0+dd+6)
        const int dn = d0 + dd + PAD + 1;
        const bool ok = (dn < NX);
        const long long o = base + (long long)(ok ? dn : 0) * (NX * NX);
        #pragma unroll
        for (int f = 0; f < NF; ++f) {
            #pragma unroll
            for (int i = 0; i < WS - 1; ++i) win[f][i] = win[f][i + 1];
            win[f][WS - 1] = ok ? A[(long long)f * PLANE + o] : 0.f;
        }
    }

    // wave reduce (64 lanes) then cross-wave via LDS
    for (int off = 32; off > 0; off >>= 1) acc += __shfl_down(acc, off, 64);
    __shared__ float wsum[4];
    if ((tid & 63) == 0) wsum[tid >> 6] = acc;
    __syncthreads();
    if (tid == 0) partial[blockIdx.x] = wsum[0] + wsum[1] + wsum[2] + wsum[3];
}

// Kernel 3: reduce partials (double), write mean.
__global__ __launch_bounds__(256) void k_red(const float* __restrict__ partial,
                                             int n, float* __restrict__ out) {
    double s = 0.0;
    for (int i = threadIdx.x; i < n; i += 256) s += (double)partial[i];
    __shared__ double sd[256];
    sd[threadIdx.x] = s;
    __syncthreads();
    for (int st = 128; st > 0; st >>= 1) {
        if (threadIdx.x < st) sd[threadIdx.x] += sd[threadIdx.x + st];
        __syncthreads();
    }
    if (threadIdx.x == 0)
        out[0] = (float)(sd[0] / (double)((long long)NB * NX * NX * NX));
}

extern "C" void kernel_launch(void* const* d_in, const int* in_sizes, int n_in,
                              void* d_out, int out_size, void* d_ws, size_t ws_size,
                              hipStream_t stream) {
    const float* x = (const float*)d_in[0];
    const float* y = (const float*)d_in[1];
    float* A = (float*)d_ws;
    float* partial = (float*)((char*)d_ws + (size_t)NF * PLANE * sizeof(float));

    GaussW gw;
    {
        float tmp[WS]; float s = 0.f;
        for (int i = 0; i < WS; ++i) {
            const double e = exp(-(double)((i - PAD) * (i - PAD)) / 4.5);
            tmp[i] = (float)e; s += tmp[i];
        }
        for (int i = 0; i < WS; ++i) gw.g[i] = tmp[i] / s;
    }

    dim3 g1(NX / TW, NX / TH, NB * NX);   // (5,8,320)
    k_wh<<<g1, 256, 0, stream>>>(x, y, A, gw);

    const int nblk2 = (NB * NX * NX * (NX / DCHUNK)) / 256;  // 800
    k_d<<<nblk2, 256, 0, stream>>>(A, partial, gw);

    k_red<<<1, 256, 0, stream>>>(partial, nblk2, (float*)d_out);
}